// Round 4
// baseline (364.199 us; speedup 1.0000x reference)
//
#include <hip/hip_runtime.h>

typedef unsigned short u16;
typedef unsigned char u8;
typedef __bf16 bf16x8 __attribute__((ext_vector_type(8)));
typedef float f32x4 __attribute__((ext_vector_type(4)));
typedef u16 u16x8 __attribute__((ext_vector_type(8)));

__device__ __forceinline__ float bf2f(u16 u) {
    union { unsigned i; float f; } c; c.i = ((unsigned)u) << 16; return c.f;
}
__device__ __forceinline__ u16 f2bf(float f) {
    union { float f; unsigned i; } c; c.f = f;
    unsigned r = c.i + 0x7FFFu + ((c.i >> 16) & 1u);
    return (u16)(r >> 16);
}

// ---------- W prep: f32 weights -> bf16 levels (q/k/v: 3 levels; proj: 1) ----------
// Wlv layout: [q0,q1,q2, k0,k1,k2, v0,v1,v2, p0] x 147456 bf16
__global__ __launch_bounds__(256) void wprep(const float* __restrict__ qw, const float* __restrict__ kw,
                                             const float* __restrict__ vw, const float* __restrict__ pw,
                                             u16* __restrict__ W) {
    int idx = blockIdx.x * 256 + threadIdx.x;          // 4*147456 = 589824
    int m = idx / 147456, e = idx % 147456;
    const float* src = m == 0 ? qw : (m == 1 ? kw : (m == 2 ? vw : pw));
    float w = src[e];
    u16 h0 = f2bf(w);  float r1 = w - bf2f(h0);
    u16 h1 = f2bf(r1); float r2 = r1 - bf2f(h1);
    u16 h2 = f2bf(r2);
    if (m < 3) {
        W[(m * 3 + 0) * 147456 + e] = h0;
        W[(m * 3 + 1) * 147456 + e] = h1;
        W[(m * 3 + 2) * 147456 + e] = h2;
    } else {
        W[9 * 147456 + e] = h0;
    }
}

// ---------- K1: shortcut LIF (f32 x) + transpose -> bf16 spikes (b,n,t,c) ----------
__global__ __launch_bounds__(256) void k1(const float* __restrict__ X, u16* __restrict__ Xt) {
    __shared__ u16 s[4][32][33];
    const int b = blockIdx.z, c0 = blockIdx.y * 32, n0 = blockIdx.x * 32;
    {
        const int n_l = threadIdx.x & 31, cg = threadIdx.x >> 5;
        for (int jj = 0; jj < 4; jj++) {
            int c_l = cg + jj * 8;
            float vm = 0.f;
            #pragma unroll
            for (int t = 0; t < 4; t++) {
                float xv = X[(((long)t * 32 + b) * 384 + c0 + c_l) * 256 + n0 + n_l];
                vm += (xv - vm) * 0.5f;
                u16 sp = 0;
                if (vm >= 1.0f) { sp = 0x3F80u; vm = 0.f; }
                s[t][c_l][n_l] = sp;
            }
        }
    }
    __syncthreads();
    {
        const int c_f = threadIdx.x & 31, ng = threadIdx.x >> 5;
        for (int jj = 0; jj < 4; jj++) {
            int n = ng + jj * 8;
            #pragma unroll
            for (int t = 0; t < 4; t++)
                Xt[(((long)b * 256 + n0 + n) * 4 + t) * 384 + c0 + c_f] = s[t][c_f][n];
        }
    }
}

// ---------- one K=384 GEMM pass, 128x128 tile, BK=32, sync staging ----------
__device__ __forceinline__ void gemm_pass(const u16* __restrict__ A, const u16* __restrict__ B,
                                          u16* As, u16* Bs, int m0, int n0, f32x4 (&acc)[4][4]) {
    const int tid = threadIdx.x, l = tid & 63, w = tid >> 6;
    const int wm = (w & 1) << 6, wn = (w >> 1) << 6;
    const int fr = l & 15, fq = (l >> 4) << 3;
    const int r0 = tid >> 2, c8 = (tid & 3) << 3, r1 = r0 + 64;
    for (int kk = 0; kk < 384; kk += 32) {
        *(u16x8*)&As[r0 * 32 + c8] = *(const u16x8*)&A[(long)(m0 + r0) * 384 + kk + c8];
        *(u16x8*)&As[r1 * 32 + c8] = *(const u16x8*)&A[(long)(m0 + r1) * 384 + kk + c8];
        *(u16x8*)&Bs[r0 * 32 + c8] = *(const u16x8*)&B[(long)(n0 + r0) * 384 + kk + c8];
        *(u16x8*)&Bs[r1 * 32 + c8] = *(const u16x8*)&B[(long)(n0 + r1) * 384 + kk + c8];
        __syncthreads();
        bf16x8 af[4], bfr[4];
        #pragma unroll
        for (int i = 0; i < 4; i++) af[i] = *(const bf16x8*)&As[(wm + (i << 4) + fr) * 32 + fq];
        #pragma unroll
        for (int j = 0; j < 4; j++) bfr[j] = *(const bf16x8*)&Bs[(wn + (j << 4) + fr) * 32 + fq];
        #pragma unroll
        for (int i = 0; i < 4; i++)
            #pragma unroll
            for (int j = 0; j < 4; j++)
                acc[i][j] = __builtin_amdgcn_mfma_f32_16x16x32_bf16(af[i], bfr[j], acc[i][j], 0, 0, 0);
        __syncthreads();
    }
}

// ---------- K2: q/k/v conv1x1 (3-level split GEMM) + BN + LIF -> spikes ----------
__global__ __launch_bounds__(256) void k2(
    const u16* __restrict__ Xt, const u16* __restrict__ Wlv,
    const float* __restrict__ g0, const float* __restrict__ b0, const float* __restrict__ m0_, const float* __restrict__ v0_,
    const float* __restrict__ g1, const float* __restrict__ b1, const float* __restrict__ m1_, const float* __restrict__ v1_,
    const float* __restrict__ g2, const float* __restrict__ b2, const float* __restrict__ m2_, const float* __restrict__ v2_,
    u16* __restrict__ oq, u8* __restrict__ ok, u8* __restrict__ ov, float* __restrict__ out1)
{
    __shared__ __attribute__((aligned(16))) float smemf[8704];   // 34816 B: staging(16K) / tile(128x136 u16)
    u16* As = (u16*)smemf;
    u16* Bs = As + 4096;
    u16* tile = (u16*)smemf;

    const int br = blockIdx.z;
    const float* G  = br == 0 ? g0  : (br == 1 ? g1  : g2);
    const float* Be = br == 0 ? b0  : (br == 1 ? b1  : b2);
    const float* Mu = br == 0 ? m0_ : (br == 1 ? m1_ : m2_);
    const float* Va = br == 0 ? v0_ : (br == 1 ? v1_ : v2_);
    const int m0 = blockIdx.x * 128, d0 = blockIdx.y * 128;

    f32x4 acc[4][4];
    for (int i = 0; i < 4; i++) for (int j = 0; j < 4; j++)
        for (int r = 0; r < 4; r++) acc[i][j][r] = 0.f;
    #pragma unroll 1
    for (int p = 0; p < 3; p++)
        gemm_pass(Xt, Wlv + (long)(br * 3 + p) * 147456, As, Bs, m0, d0, acc);

    const int tid = threadIdx.x, l = tid & 63, w = tid >> 6;
    const int wm = (w & 1) << 6, wn = (w >> 1) << 6;
    const int fr = l & 15, fq = l >> 4;
    float sc[4], mu[4], be[4];
    #pragma unroll
    for (int j = 0; j < 4; j++) {
        int d = d0 + wn + (j << 4) + fr;
        sc[j] = G[d] / sqrtf(Va[d] + 1e-5f);
        mu[j] = Mu[d];
        be[j] = Be[d];
    }
    // BN + LIF (t = reg index r; m = (b,n,t), t innermost) -> spike tile
    #pragma unroll
    for (int i = 0; i < 4; i++)
        #pragma unroll
        for (int j = 0; j < 4; j++) {
            float vm = 0.f;
            #pragma unroll
            for (int r = 0; r < 4; r++) {
                float bn = (acc[i][j][r] - mu[j]) * sc[j] + be[j];
                vm += (bn - vm) * 0.5f;
                u16 s = 0;
                if (vm >= 1.0f) { s = 0x3F80u; vm = 0.f; }
                tile[(wm + (i << 4) + (fq << 2) + r) * 136 + wn + (j << 4) + fr] = s;
            }
        }
    __syncthreads();
    const int c8 = (tid & 15) << 3;
    if (br == 0) {
        #pragma unroll
        for (int p = 0; p < 8; p++) {
            int ml = (tid >> 4) + (p << 4);
            *(u16x8*)&oq[(long)(m0 + ml) * 384 + d0 + c8] = *(const u16x8*)&tile[ml * 136 + c8];
        }
    } else {
        u8* Out8 = (br == 1) ? ok : ov;
        #pragma unroll
        for (int p = 0; p < 8; p++) {
            int ml = (tid >> 4) + (p << 4);
            u16x8 sp = *(const u16x8*)&tile[ml * 136 + c8];
            union { u8 b[8]; uint2 u; } pk;
            #pragma unroll
            for (int r = 0; r < 8; r++) pk.b[r] = sp[r] ? 1 : 0;
            *(uint2*)&Out8[(long)(m0 + ml) * 384 + d0 + c8] = pk.u;
        }
        if (br == 2) {   // output 1: v spikes as f32 in (T,B,h,N,Ch)
            const int b = m0 >> 10, n_base = (m0 >> 2) & 255;
            const int dl = tid & 127, d = d0 + dl;
            const int h = d / 48, ch = d % 48;
            for (int q = 0; q < 64; q++) {
                int ml = (tid >> 7) + (q << 1);
                int t = ml & 3, n = n_base + (ml >> 2);
                out1[((((long)t * 32 + b) * 8 + h) * 256 + n) * 48 + ch] =
                    tile[ml * 136 + dl] ? 1.0f : 0.f;
            }
        }
    }
}

// ---------- K3a: kv partial counts (exact int) ----------
__global__ __launch_bounds__(384) void k3a(const u8* __restrict__ Ks, const u8* __restrict__ Vs,
                                           float* __restrict__ kv_raw) {
    const int b = blockIdx.y, nc = blockIdx.x, d = threadIdx.x;
    int cnt[4] = {0, 0, 0, 0};
    for (int nl = 0; nl < 32; nl++) {
        const long rb = ((long)b * 256 + nc * 32 + nl) * 4;
        #pragma unroll
        for (int t = 0; t < 4; t++)
            cnt[t] += (Ks[(rb + t) * 384 + d] & Vs[(rb + t) * 384 + d]);
    }
    #pragma unroll
    for (int t = 0; t < 4; t++)
        atomicAdd(&kv_raw[((long)t * 32 + b) * 384 + d], (float)cnt[t]);
}

// ---------- K3b: LIF(kv, v_th=0.5) — exact dyadic arithmetic ----------
__global__ __launch_bounds__(384) void k3b(const float* __restrict__ kv_raw, u16* __restrict__ kvs) {
    const int b = blockIdx.x, d = threadIdx.x;
    float vm = 0.f;
    #pragma unroll
    for (int t = 0; t < 4; t++) {
        vm += (kv_raw[((long)t * 32 + b) * 384 + d] - vm) * 0.5f;
        u16 sp = 0;
        if (vm >= 0.5f) { sp = 0x3F80u; vm = 0.f; }
        kvs[((long)t * 32 + b) * 384 + d] = sp;
    }
}

// ---------- K3c: y = q & kv (bitwise AND == exact {0,1} multiply) ----------
__global__ __launch_bounds__(256) void k3c(const u16* __restrict__ Qs, const u16* __restrict__ KVs,
                                           u16* __restrict__ Y) {
    const long i8 = ((long)blockIdx.x * 256 + threadIdx.x) * 8;
    const int m = (int)(i8 / 384), d8 = (int)(i8 % 384);
    const int t = m & 3, b = m >> 10;
    uint4 qv = *(const uint4*)(Qs + i8);
    uint4 kv = *(const uint4*)(KVs + ((long)(t * 32 + b) * 384 + d8));
    uint4 yv;
    yv.x = qv.x & kv.x; yv.y = qv.y & kv.y; yv.z = qv.z & kv.z; yv.w = qv.w & kv.w;
    *(uint4*)(Y + i8) = yv;
}

// ---------- K4: proj GEMM + bias + BN + identity -> f32 (T,B,C,H,W) ----------
__global__ __launch_bounds__(256) void k4(
    const u16* __restrict__ Y, const u16* __restrict__ PW,
    const float* __restrict__ PB, const float* __restrict__ PG, const float* __restrict__ PBe,
    const float* __restrict__ PM, const float* __restrict__ PV,
    const float* __restrict__ X, float* __restrict__ O)
{
    __shared__ __attribute__((aligned(16))) float smemf[8704];   // staging / f32 tile 64x136
    u16* As = (u16*)smemf;
    u16* Bs = As + 4096;

    const int m0 = blockIdx.x * 128, e0 = blockIdx.y * 128;
    f32x4 acc[4][4];
    for (int i = 0; i < 4; i++) for (int j = 0; j < 4; j++)
        for (int r = 0; r < 4; r++) acc[i][j][r] = 0.f;
    gemm_pass(Y, PW, As, Bs, m0, e0, acc);

    const int tid = threadIdx.x, l = tid & 63, w = tid >> 6;
    const int wm = (w & 1) << 6, wn = (w >> 1) << 6;
    const int fr = l & 15, fq = l >> 4;
    float sc[4], mu[4], be[4], pb[4];
    #pragma unroll
    for (int j = 0; j < 4; j++) {
        int e = e0 + wn + (j << 4) + fr;
        sc[j] = PG[e] / sqrtf(PV[e] + 1e-5f);
        mu[j] = PM[e];
        be[j] = PBe[e];
        pb[j] = PB[e];
    }
    const int b = m0 >> 10, n_base = (m0 >> 2) & 255;
    // two half-tiles of 64 m-rows (16 n x 4 t) to fit f32 LDS
    for (int cchunk = 0; cchunk < 2; cchunk++) {
        if ((w & 1) == cchunk) {
            #pragma unroll
            for (int i = 0; i < 4; i++)
                #pragma unroll
                for (int j = 0; j < 4; j++)
                    #pragma unroll
                    for (int r = 0; r < 4; r++) {
                        float z = (acc[i][j][r] + pb[j] - mu[j]) * sc[j] + be[j];
                        smemf[((i << 4) + (fq << 2) + r) * 136 + wn + (j << 4) + fr] = z;
                    }
        }
        __syncthreads();
        const int n_l = tid & 15, eg = tid >> 4;
        #pragma unroll
        for (int ee = 0; ee < 8; ee++) {
            int e_l = eg + (ee << 4);
            #pragma unroll
            for (int t = 0; t < 4; t++) {
                float z = smemf[((n_l << 2) + t) * 136 + e_l];
                long gi = (((long)t * 32 + b) * 384 + e0 + e_l) * 256 + n_base + (cchunk << 4) + n_l;
                O[gi] = z + X[gi];
            }
        }
        __syncthreads();
    }
}

extern "C" void kernel_launch(void* const* d_in, const int* in_sizes, int n_in,
                              void* d_out, int out_size, void* d_ws, size_t ws_size,
                              hipStream_t stream) {
    (void)in_sizes; (void)n_in; (void)out_size; (void)ws_size;
    const float* x   = (const float*)d_in[0];
    const float* qw  = (const float*)d_in[1];
    const float* qg  = (const float*)d_in[2];
    const float* qb  = (const float*)d_in[3];
    const float* qm  = (const float*)d_in[4];
    const float* qv  = (const float*)d_in[5];
    const float* kw  = (const float*)d_in[6];
    const float* kg  = (const float*)d_in[7];
    const float* kb  = (const float*)d_in[8];
    const float* km  = (const float*)d_in[9];
    const float* kv  = (const float*)d_in[10];
    const float* vw  = (const float*)d_in[11];
    const float* vg  = (const float*)d_in[12];
    const float* vb  = (const float*)d_in[13];
    const float* vm  = (const float*)d_in[14];
    const float* vv  = (const float*)d_in[15];
    const float* pw  = (const float*)d_in[16];
    const float* pb  = (const float*)d_in[17];
    const float* pg  = (const float*)d_in[18];
    const float* pbe = (const float*)d_in[19];
    const float* pm  = (const float*)d_in[20];
    const float* pv  = (const float*)d_in[21];

    // d_out (201 MB f32) doubles as scratch:
    //   out0 lower 25 MB: Xt bf16 spikes; out0 upper 25 MB: Qs bf16 spikes (both dead before k4 writes out0)
    //   out1: written directly by k2's v-branch epilogue
    // ws (28.4 MB): Ks/Vs u8 (-> reused as Y bf16 after k3a), KVraw, KVs, weight levels
    float* out0 = (float*)d_out;
    float* out1 = out0 + 12582912;
    u16*   Xt   = (u16*)out0;
    u16*   Qs   = (u16*)out0 + 12582912;
    char*  ws   = (char*)d_ws;
    u8*    Ks8  = (u8*)ws;                       // 12582912
    u8*    Vs8  = (u8*)ws + 12582912;            // 12582912
    u16*   Yb   = (u16*)ws;                      // reuse after k3a
    float* KVraw = (float*)(ws + 25165824);      // 196608 B
    u16*   KVs   = (u16*)(ws + 25362432);        // 98304 B
    u16*   Wlv   = (u16*)(ws + 25460736);        // 2949120 B

    hipMemsetAsync(KVraw, 0, 196608, stream);
    hipLaunchKernelGGL(wprep, dim3(2304), dim3(256), 0, stream, qw, kw, vw, pw, Wlv);
    hipLaunchKernelGGL(k1, dim3(8, 12, 32), dim3(256), 0, stream, x, Xt);
    hipLaunchKernelGGL(k2, dim3(256, 3, 3), dim3(256), 0, stream,
                       Xt, Wlv,
                       qg, qb, qm, qv,
                       kg, kb, km, kv,
                       vg, vb, vm, vv,
                       Qs, Ks8, Vs8, out1);
    hipLaunchKernelGGL(k3a, dim3(8, 32), dim3(384), 0, stream, Ks8, Vs8, KVraw);
    hipLaunchKernelGGL(k3b, dim3(32), dim3(384), 0, stream, KVraw, KVs);
    hipLaunchKernelGGL(k3c, dim3(6144), dim3(256), 0, stream, Qs, KVs, Yb);
    hipLaunchKernelGGL(k4, dim3(256, 3), dim3(256), 0, stream,
                       Yb, Wlv + 9 * 147456, pb, pg, pbe, pm, pv, x, out0);
}

// Round 5
// 336.920 us; speedup vs baseline: 1.0810x; 1.0810x over previous
//
#include <hip/hip_runtime.h>

typedef unsigned short u16;
typedef unsigned char u8;
typedef __bf16 bf16x8 __attribute__((ext_vector_type(8)));
typedef float f32x4 __attribute__((ext_vector_type(4)));
typedef u16 u16x8 __attribute__((ext_vector_type(8)));

__device__ __forceinline__ float bf2f(u16 u) {
    union { unsigned i; float f; } c; c.i = ((unsigned)u) << 16; return c.f;
}
__device__ __forceinline__ u16 f2bf(float f) {
    union { float f; unsigned i; } c; c.f = f;
    unsigned r = c.i + 0x7FFFu + ((c.i >> 16) & 1u);
    return (u16)(r >> 16);
}

// ---------- PREP: fused [k1: shortcut LIF + transpose] + [weight levels] + [KVraw zero] ----------
// grid: 768 k1-blocks (3 c-tiles x 8 n-tiles x 32 b) + 576 weight blocks; block 256
__global__ __launch_bounds__(256) void prep(const float* __restrict__ X, u16* __restrict__ Xt,
    const float* __restrict__ qw, const float* __restrict__ kw,
    const float* __restrict__ vw, const float* __restrict__ pw,
    u16* __restrict__ W, float* __restrict__ KVraw) {
    const int bid = blockIdx.x;
    if (bid < 768) {
        __shared__ u16 s[4][128][33];
        const int c0 = (bid % 3) * 128;
        const int n0 = ((bid / 3) & 7) * 32;
        const int b = bid / 24;
        const int n_l = threadIdx.x & 31, cg = threadIdx.x >> 5;
        for (int jj = 0; jj < 16; jj++) {
            int c_l = cg + jj * 8;
            float vm = 0.f;
            #pragma unroll
            for (int t = 0; t < 4; t++) {
                float xv = X[(((long)t * 32 + b) * 384 + c0 + c_l) * 256 + n0 + n_l];
                vm += (xv - vm) * 0.5f;
                u16 sp = 0;
                if (vm >= 1.0f) { sp = 0x3F80u; vm = 0.f; }
                s[t][c_l][n_l] = sp;
            }
        }
        __syncthreads();
        const int c8 = (threadIdx.x & 15) << 3;
        const int ng = threadIdx.x >> 4;
        for (int half = 0; half < 2; half++) {
            int n = ng + half * 16;
            #pragma unroll
            for (int t = 0; t < 4; t++) {
                u16x8 v;
                #pragma unroll
                for (int j = 0; j < 8; j++) v[j] = s[t][c8 + j][n];
                *(u16x8*)&Xt[(((long)b * 256 + n0 + n) * 4 + t) * 384 + c0 + c8] = v;
            }
        }
    } else {
        const int idx = (bid - 768) * 256 + threadIdx.x;   // [0, 147456)
        const float* srcs[3] = {qw, kw, vw};
        #pragma unroll
        for (int m = 0; m < 3; m++) {
            float w = srcs[m][idx];
            u16 h0 = f2bf(w);  float r1 = w - bf2f(h0);
            u16 h1 = f2bf(r1); float r2 = r1 - bf2f(h1);
            u16 h2 = f2bf(r2);
            W[(m * 3 + 0) * 147456 + idx] = h0;
            W[(m * 3 + 1) * 147456 + idx] = h1;
            W[(m * 3 + 2) * 147456 + idx] = h2;
        }
        W[9 * 147456 + idx] = f2bf(pw[idx]);
        if (idx < 49152) KVraw[idx] = 0.f;
    }
}

// ---------- multi-level GEMM K-loop: 128x128 tile, BK=32, padded LDS (stride 40), A staged once ----------
template<int NL>
__device__ __forceinline__ void gemm_levels(const u16* __restrict__ A, const u16* __restrict__ B,
                                            long lstride, u16* lds, int m0, int n0, f32x4 (&acc)[4][4]) {
    const int tid = threadIdx.x, l = tid & 63, w = tid >> 6;
    const int wm = (w & 1) << 6, wn = (w >> 1) << 6;
    const int fr = l & 15, fq = (l >> 4) << 3;
    const int r0 = tid >> 2, c8 = (tid & 3) << 3, r1 = r0 + 64;
    const u16* Ap0 = A + (long)(m0 + r0) * 384 + c8;
    const u16* Ap1 = A + (long)(m0 + r1) * 384 + c8;
    const u16* Bp0 = B + (long)(n0 + r0) * 384 + c8;
    const u16* Bp1 = B + (long)(n0 + r1) * 384 + c8;
    u16x8 pa0 = *(const u16x8*)Ap0;
    u16x8 pa1 = *(const u16x8*)Ap1;
    u16x8 pb[NL][2];
    #pragma unroll
    for (int p = 0; p < NL; p++) {
        pb[p][0] = *(const u16x8*)(Bp0 + p * lstride);
        pb[p][1] = *(const u16x8*)(Bp1 + p * lstride);
    }
    for (int kk = 0; kk < 384; kk += 32) {
        *(u16x8*)&lds[r0 * 40 + c8] = pa0;
        *(u16x8*)&lds[r1 * 40 + c8] = pa1;
        #pragma unroll
        for (int p = 0; p < NL; p++) {
            *(u16x8*)&lds[5120 + p * 5120 + r0 * 40 + c8] = pb[p][0];
            *(u16x8*)&lds[5120 + p * 5120 + r1 * 40 + c8] = pb[p][1];
        }
        __syncthreads();
        if (kk + 32 < 384) {
            pa0 = *(const u16x8*)(Ap0 + kk + 32);
            pa1 = *(const u16x8*)(Ap1 + kk + 32);
            #pragma unroll
            for (int p = 0; p < NL; p++) {
                pb[p][0] = *(const u16x8*)(Bp0 + p * lstride + kk + 32);
                pb[p][1] = *(const u16x8*)(Bp1 + p * lstride + kk + 32);
            }
        }
        bf16x8 af[4];
        #pragma unroll
        for (int i = 0; i < 4; i++) af[i] = *(const bf16x8*)&lds[(wm + (i << 4) + fr) * 40 + fq];
        #pragma unroll
        for (int p = 0; p < NL; p++)
            #pragma unroll
            for (int j = 0; j < 4; j++) {
                bf16x8 bfr = *(const bf16x8*)&lds[5120 + p * 5120 + (wn + (j << 4) + fr) * 40 + fq];
                #pragma unroll
                for (int i = 0; i < 4; i++)
                    acc[i][j] = __builtin_amdgcn_mfma_f32_16x16x32_bf16(af[i], bfr, acc[i][j], 0, 0, 0);
            }
        __syncthreads();
    }
}

// ---------- K2: q/k/v conv1x1 (3-level split GEMM) + BN + LIF -> u8 spikes ----------
__global__ __launch_bounds__(256) void k2(
    const u16* __restrict__ Xt, const u16* __restrict__ Wlv,
    const float* __restrict__ g0, const float* __restrict__ b0, const float* __restrict__ m0_, const float* __restrict__ v0_,
    const float* __restrict__ g1, const float* __restrict__ b1, const float* __restrict__ m1_, const float* __restrict__ v1_,
    const float* __restrict__ g2, const float* __restrict__ b2, const float* __restrict__ m2_, const float* __restrict__ v2_,
    u8* __restrict__ oq, u8* __restrict__ ok, u8* __restrict__ ov, float* __restrict__ out1)
{
    __shared__ __attribute__((aligned(16))) u16 lds[20480];   // staging 40960 B; tile 128x136 aliased
    const int br = blockIdx.z;
    const float* G  = br == 0 ? g0  : (br == 1 ? g1  : g2);
    const float* Be = br == 0 ? b0  : (br == 1 ? b1  : b2);
    const float* Mu = br == 0 ? m0_ : (br == 1 ? m1_ : m2_);
    const float* Va = br == 0 ? v0_ : (br == 1 ? v1_ : v2_);
    const int m0 = blockIdx.x * 128, d0 = blockIdx.y * 128;

    f32x4 acc[4][4];
    for (int i = 0; i < 4; i++) for (int j = 0; j < 4; j++)
        for (int r = 0; r < 4; r++) acc[i][j][r] = 0.f;
    gemm_levels<3>(Xt, Wlv + (long)br * 3 * 147456, 147456L, lds, m0, d0, acc);

    const int tid = threadIdx.x, l = tid & 63, w = tid >> 6;
    const int wm = (w & 1) << 6, wn = (w >> 1) << 6;
    const int fr = l & 15, fq = l >> 4;
    float sc[4], mu[4], be[4];
    #pragma unroll
    for (int j = 0; j < 4; j++) {
        int d = d0 + wn + (j << 4) + fr;
        sc[j] = G[d] / sqrtf(Va[d] + 1e-5f);
        mu[j] = Mu[d];
        be[j] = Be[d];
    }
    u16* tile = lds;
    #pragma unroll
    for (int i = 0; i < 4; i++)
        #pragma unroll
        for (int j = 0; j < 4; j++) {
            float vm = 0.f;
            #pragma unroll
            for (int r = 0; r < 4; r++) {
                float bn = (acc[i][j][r] - mu[j]) * sc[j] + be[j];
                vm += (bn - vm) * 0.5f;
                u16 s = 0;
                if (vm >= 1.0f) { s = 0x3F80u; vm = 0.f; }
                tile[(wm + (i << 4) + (fq << 2) + r) * 136 + wn + (j << 4) + fr] = s;
            }
        }
    __syncthreads();
    const int c8 = (tid & 15) << 3;
    u8* Out8 = br == 0 ? oq : (br == 1 ? ok : ov);
    #pragma unroll
    for (int p = 0; p < 8; p++) {
        int ml = (tid >> 4) + (p << 4);
        u16x8 sp = *(const u16x8*)&tile[ml * 136 + c8];
        union { u8 b[8]; uint2 u; } pk;
        #pragma unroll
        for (int r = 0; r < 8; r++) pk.b[r] = sp[r] ? 1 : 0;
        *(uint2*)&Out8[(long)(m0 + ml) * 384 + d0 + c8] = pk.u;
    }
    if (br == 2) {   // output 1: v spikes as f32 in (T,B,h,N,Ch)
        const int b = m0 >> 10, n_base = (m0 >> 2) & 255;
        const int dl = tid & 127, d = d0 + dl;
        const int h = d / 48, ch = d % 48;
        for (int q = 0; q < 64; q++) {
            int ml = (tid >> 7) + (q << 1);
            int t = ml & 3, n = n_base + (ml >> 2);
            out1[((((long)t * 32 + b) * 8 + h) * 256 + n) * 48 + ch] =
                tile[ml * 136 + dl] ? 1.0f : 0.f;
        }
    }
}

// ---------- K3a: kv partial counts (exact int), uchar4 loads ----------
// block (96,4): tidx = d-quad, tidy = t; grid (8 n-chunks, 32 b)
__global__ __launch_bounds__(384) void k3a(const u8* __restrict__ Ks, const u8* __restrict__ Vs,
                                           float* __restrict__ kv_raw) {
    const int b = blockIdx.y, nc = blockIdx.x;
    const int d4 = threadIdx.x * 4, t = threadIdx.y;
    int cnt0 = 0, cnt1 = 0, cnt2 = 0, cnt3 = 0;
    for (int nl = 0; nl < 32; nl++) {
        const long row = ((long)b * 256 + nc * 32 + nl) * 4 + t;
        uchar4 kk = *(const uchar4*)&Ks[row * 384 + d4];
        uchar4 vv = *(const uchar4*)&Vs[row * 384 + d4];
        cnt0 += (kk.x & vv.x); cnt1 += (kk.y & vv.y);
        cnt2 += (kk.z & vv.z); cnt3 += (kk.w & vv.w);
    }
    float* dst = &kv_raw[((long)t * 32 + b) * 384 + d4];
    atomicAdd(dst + 0, (float)cnt0);
    atomicAdd(dst + 1, (float)cnt1);
    atomicAdd(dst + 2, (float)cnt2);
    atomicAdd(dst + 3, (float)cnt3);
}

// ---------- K3b: LIF(kv, v_th=0.5) ----------
__global__ __launch_bounds__(384) void k3b(const float* __restrict__ kv_raw, u16* __restrict__ kvs) {
    const int b = blockIdx.x, d = threadIdx.x;
    float vm = 0.f;
    #pragma unroll
    for (int t = 0; t < 4; t++) {
        vm += (kv_raw[((long)t * 32 + b) * 384 + d] - vm) * 0.5f;
        u16 sp = 0;
        if (vm >= 0.5f) { sp = 0x3F80u; vm = 0.f; }
        kvs[((long)t * 32 + b) * 384 + d] = sp;
    }
}

// ---------- K3c: Y(bf16) = q(u8) * KV(bf16 mask) ----------
__global__ __launch_bounds__(256) void k3c(const u8* __restrict__ Qs, const u16* __restrict__ KVs,
                                           u16* __restrict__ Y) {
    const long i8 = ((long)blockIdx.x * 256 + threadIdx.x) * 8;
    const int m = (int)(i8 / 384), d8 = (int)(i8 % 384);
    const int t = m & 3, b = m >> 10;
    uint2 q8 = *(const uint2*)(Qs + i8);
    const u8* qb = (const u8*)&q8;
    u16x8 kv = *(const u16x8*)(KVs + ((long)(t * 32 + b) * 384 + d8));
    u16x8 y;
    #pragma unroll
    for (int j = 0; j < 8; j++) y[j] = qb[j] ? kv[j] : (u16)0;
    *(u16x8*)(Y + i8) = y;
}

// ---------- K4: proj GEMM + bias + BN + identity -> f32 (T,B,C,H,W) ----------
__global__ __launch_bounds__(256) void k4(
    const u16* __restrict__ Y, const u16* __restrict__ PW,
    const float* __restrict__ PB, const float* __restrict__ PG, const float* __restrict__ PBe,
    const float* __restrict__ PM, const float* __restrict__ PV,
    const float* __restrict__ X, float* __restrict__ O)
{
    __shared__ __attribute__((aligned(16))) u16 lds[20480];
    const int m0 = blockIdx.x * 128, e0 = blockIdx.y * 128;
    f32x4 acc[4][4];
    for (int i = 0; i < 4; i++) for (int j = 0; j < 4; j++)
        for (int r = 0; r < 4; r++) acc[i][j][r] = 0.f;
    gemm_levels<1>(Y, PW, 0L, lds, m0, e0, acc);

    const int tid = threadIdx.x, l = tid & 63, w = tid >> 6;
    const int wm = (w & 1) << 6, wn = (w >> 1) << 6;
    const int fr = l & 15, fq = l >> 4;
    float sc[4], mu[4], be[4], pb[4];
    #pragma unroll
    for (int j = 0; j < 4; j++) {
        int e = e0 + wn + (j << 4) + fr;
        sc[j] = PG[e] / sqrtf(PV[e] + 1e-5f);
        mu[j] = PM[e];
        be[j] = PBe[e];
        pb[j] = PB[e];
    }
    float* smemf = (float*)lds;   // 64x136 f32 tile = 34816 B <= 40960
    const int b = m0 >> 10, n_base = (m0 >> 2) & 255;
    for (int cchunk = 0; cchunk < 2; cchunk++) {
        if ((w & 1) == cchunk) {
            #pragma unroll
            for (int i = 0; i < 4; i++)
                #pragma unroll
                for (int j = 0; j < 4; j++)
                    #pragma unroll
                    for (int r = 0; r < 4; r++) {
                        float z = (acc[i][j][r] + pb[j] - mu[j]) * sc[j] + be[j];
                        smemf[((i << 4) + (fq << 2) + r) * 136 + wn + (j << 4) + fr] = z;
                    }
        }
        __syncthreads();
        const int n_l = tid & 15, eg = tid >> 4;
        #pragma unroll
        for (int ee = 0; ee < 8; ee++) {
            int e_l = eg + (ee << 4);
            #pragma unroll
            for (int t = 0; t < 4; t++) {
                float z = smemf[((n_l << 2) + t) * 136 + e_l];
                long gi = (((long)t * 32 + b) * 384 + e0 + e_l) * 256 + n_base + (cchunk << 4) + n_l;
                O[gi] = z + X[gi];
            }
        }
        __syncthreads();
    }
}

extern "C" void kernel_launch(void* const* d_in, const int* in_sizes, int n_in,
                              void* d_out, int out_size, void* d_ws, size_t ws_size,
                              hipStream_t stream) {
    (void)in_sizes; (void)n_in; (void)out_size; (void)ws_size;
    const float* x   = (const float*)d_in[0];
    const float* qw  = (const float*)d_in[1];
    const float* qg  = (const float*)d_in[2];
    const float* qb  = (const float*)d_in[3];
    const float* qm  = (const float*)d_in[4];
    const float* qv  = (const float*)d_in[5];
    const float* kw  = (const float*)d_in[6];
    const float* kg  = (const float*)d_in[7];
    const float* kb  = (const float*)d_in[8];
    const float* km  = (const float*)d_in[9];
    const float* kv  = (const float*)d_in[10];
    const float* vw  = (const float*)d_in[11];
    const float* vg  = (const float*)d_in[12];
    const float* vb  = (const float*)d_in[13];
    const float* vm  = (const float*)d_in[14];
    const float* vv  = (const float*)d_in[15];
    const float* pw  = (const float*)d_in[16];
    const float* pb  = (const float*)d_in[17];
    const float* pg  = (const float*)d_in[18];
    const float* pbe = (const float*)d_in[19];
    const float* pm  = (const float*)d_in[20];
    const float* pv  = (const float*)d_in[21];

    // out0 (50.3 MB) as scratch until k4 writes it:
    //   Qs8 u8 @ [0, 12582912)  (dead after k3c)
    //   Xt  u16 @ [12582912, 37748736)  (dead after k2)
    // ws (28.4 MB): Ks8/Vs8 u8 (-> reused as Y bf16 after k3a), KVraw, KVs, Wlv
    float* out0 = (float*)d_out;
    float* out1 = out0 + 12582912;
    char*  ob   = (char*)d_out;
    u8*    Qs8  = (u8*)ob;
    u16*   Xt   = (u16*)(ob + 12582912);
    char*  ws   = (char*)d_ws;
    u8*    Ks8  = (u8*)ws;
    u8*    Vs8  = (u8*)ws + 12582912;
    u16*   Yb   = (u16*)ws;                      // reuse Ks8+Vs8 after k3a
    float* KVraw = (float*)(ws + 25165824);      // 196608 B
    u16*   KVs   = (u16*)(ws + 25362432);        // 98304 B
    u16*   Wlv   = (u16*)(ws + 25460736);        // 2949120 B

    hipLaunchKernelGGL(prep, dim3(1344), dim3(256), 0, stream, x, Xt, qw, kw, vw, pw, Wlv, KVraw);
    hipLaunchKernelGGL(k2, dim3(256, 3, 3), dim3(256), 0, stream,
                       Xt, Wlv,
                       qg, qb, qm, qv,
                       kg, kb, km, kv,
                       vg, vb, vm, vv,
                       Qs8, Ks8, Vs8, out1);
    hipLaunchKernelGGL(k3a, dim3(8, 32), dim3(96, 4), 0, stream, Ks8, Vs8, KVraw);
    hipLaunchKernelGGL(k3b, dim3(32), dim3(384), 0, stream, KVraw, KVs);
    hipLaunchKernelGGL(k3c, dim3(6144), dim3(256), 0, stream, Qs8, KVs, Yb);
    hipLaunchKernelGGL(k4, dim3(256, 3), dim3(256), 0, stream,
                       Yb, Wlv + 9 * 147456, pb, pg, pbe, pm, pv, x, out0);
}